// Round 7
// baseline (266.393 us; speedup 1.0000x reference)
//
#include <hip/hip_runtime.h>
#include <hip/hip_fp16.h>
#include <stdint.h>

#define O_FEAT 4096
#define I_FEAT 4096
#define M_DIM  2048
#define K_DIM  4096

typedef __attribute__((ext_vector_type(8))) short short8;   // 8 x bf16 (4 VGPRs)
typedef __attribute__((ext_vector_type(2))) short short2v;  // 2 x bf16 (1 VGPR)
typedef __attribute__((ext_vector_type(4))) float floatx4;  // MFMA accumulator

#define AS1 __attribute__((address_space(1)))
#define AS3 __attribute__((address_space(3)))

__device__ __forceinline__ uint16_t f32_to_bf16(float f) {
    uint32_t u = __builtin_bit_cast(uint32_t, f);
    u = (u + 0x7FFFu + ((u >> 16) & 1u)) >> 16;   // round-to-nearest-even
    return (uint16_t)u;
}
__device__ __forceinline__ float bf16_to_f32(uint16_t h) {
    uint32_t u = ((uint32_t)h) << 16;
    return __builtin_bit_cast(float, u);
}

// async global->LDS, 16B per lane; LDS dest = wave-uniform base + lane*16
__device__ __forceinline__ void load_lds16(const uint16_t* gptr, uint16_t* ldsptr) {
    __builtin_amdgcn_global_load_lds((const AS1 uint32_t*)gptr,
                                     (AS3 uint32_t*)ldsptr, 16, 0, 0);
}

// ---------------------------------------------------------------------------
// Kernel 1: dequant int4 -> bf16 W.  (R1-exact)
// ---------------------------------------------------------------------------
__global__ __launch_bounds__(256) void dequant_kernel(
        const void*  __restrict__ packed,
        const float* __restrict__ scales,
        uint16_t*    __restrict__ W) {
    const int lane = threadIdx.x & 63;
    uint32_t probe = ((const uint32_t*)packed)[lane];
    const bool int32mode = (__ballot(probe >= 256u) == 0ull);

    int idx = blockIdx.x * 256 + threadIdx.x;       // 2,097,152 threads
    float s = scales[idx >> 9];                     // 512 byte-quads per row

    uint32_t bytes4;
    if (int32mode) {
        uint4 w = ((const uint4*)packed)[idx];      // 4 int32, each 0..255
        bytes4 = (w.x & 0xFFu) | ((w.y & 0xFFu) << 8) |
                 ((w.z & 0xFFu) << 16) | ((w.w & 0xFFu) << 24);
    } else {
        bytes4 = ((const uint32_t*)packed)[idx];
    }

    uint16_t o[8];
#pragma unroll
    for (int b = 0; b < 4; ++b) {
        int byte = (bytes4 >> (8 * b)) & 0xFF;
        o[2 * b]     = f32_to_bf16((float)((byte & 0xF) - 8) * s);  // low -> even
        o[2 * b + 1] = f32_to_bf16((float)((byte >> 4) - 8) * s);   // high -> odd
    }
    uint4 v;
    v.x = (uint32_t)o[0] | ((uint32_t)o[1] << 16);
    v.y = (uint32_t)o[2] | ((uint32_t)o[3] << 16);
    v.z = (uint32_t)o[4] | ((uint32_t)o[5] << 16);
    v.w = (uint32_t)o[6] | ((uint32_t)o[7] << 16);
    ((uint4*)W)[idx] = v;
}

// ---------------------------------------------------------------------------
// Kernel 2 (fused): [0,3328) scatter COO residual into W; [3328,7424)
// x -> bf16 Xb; [7424,15616) zero C (split-K GEMM atomically accumulates).
// ---------------------------------------------------------------------------
#define SCATTER_BLOCKS 3328
#define XCONV_END      7424
#define K2_BLOCKS      15616
__global__ __launch_bounds__(256) void scatter_xconv_zero_kernel(
        const void*  __restrict__ vals,
        const int*   __restrict__ rows,
        const int*   __restrict__ cols,
        const float* __restrict__ alpha,
        const float* __restrict__ x,
        uint16_t*    __restrict__ W,
        uint16_t*    __restrict__ Xb,
        float*       __restrict__ C,
        int nnz) {
    if (blockIdx.x < SCATTER_BLOCKS) {
        const int lane = threadIdx.x & 63;
        float p = fabsf(((const float*)vals)[lane]);
        int cnt = __popcll(__ballot(p > 1e-4f && p < 1.0f));
        const bool f32mode = (cnt >= 32);

        int i = blockIdx.x * 256 + threadIdx.x;
        if (i >= nnz) return;
        float v = f32mode ? ((const float*)vals)[i]
                          : __half2float(((const __half*)vals)[i]);
        v *= alpha[0];
        int r = rows[i], c = cols[i];
        size_t elem = (size_t)r * I_FEAT + c;

#if __has_builtin(__builtin_amdgcn_global_atomic_fadd_v2bf16)
        const bool hi = (elem & 1);
        short b = (short)f32_to_bf16(v);
        short2v val;
        val[0] = hi ? (short)0 : b;
        val[1] = hi ? b : (short)0;
        __builtin_amdgcn_global_atomic_fadd_v2bf16(
            (AS1 short2v*)(W + (elem & ~(size_t)1)), val);
#else
        uint32_t* word = (uint32_t*)W + (elem >> 1);
        bool hi = (c & 1);
        uint32_t old = *word, assumed;
        do {
            assumed = old;
            uint16_t cur = hi ? (uint16_t)(assumed >> 16) : (uint16_t)(assumed & 0xFFFF);
            uint16_t nw  = f32_to_bf16(bf16_to_f32(cur) + v);
            uint32_t neww = hi ? ((assumed & 0x0000FFFFu) | ((uint32_t)nw << 16))
                               : ((assumed & 0xFFFF0000u) | (uint32_t)nw);
            old = atomicCAS(word, assumed, neww);
        } while (old != assumed);
#endif
    } else if (blockIdx.x < XCONV_END) {
        int idx = (blockIdx.x - SCATTER_BLOCKS) * 256 + threadIdx.x;  // 1,048,576
        float4 v0 = ((const float4*)x)[2 * idx];
        float4 v1 = ((const float4*)x)[2 * idx + 1];
        uint4 o;
        o.x = (uint32_t)f32_to_bf16(v0.x) | ((uint32_t)f32_to_bf16(v0.y) << 16);
        o.y = (uint32_t)f32_to_bf16(v0.z) | ((uint32_t)f32_to_bf16(v0.w) << 16);
        o.z = (uint32_t)f32_to_bf16(v1.x) | ((uint32_t)f32_to_bf16(v1.y) << 16);
        o.w = (uint32_t)f32_to_bf16(v1.z) | ((uint32_t)f32_to_bf16(v1.w) << 16);
        ((uint4*)Xb)[idx] = o;
    } else {
        // zero C: 8192 blocks x 256 thr x 16B = 32 MB exact
        int zidx = (blockIdx.x - XCONV_END) * 256 + threadIdx.x;
        ((uint4*)C)[zidx] = uint4{0u, 0u, 0u, 0u};
    }
}

// ---------------------------------------------------------------------------
// Kernel 3: C[M,N] += A[M,K] * B[N,K]^T  (bf16 in, fp32 atomic-accum out).
// R14: 256x256 tile + SPLIT-K=2.  Evidence: R9(4-phase,1blk)=2798 cyc/tile,
// R13(4-phase,2blk)=2771, R10(fat)=2910 — the floor is per-phase overhead
// (~390 cyc) over only 8 MFMA/wave/phase.  m201 (16 MFMA/phase, same barrier
// pattern) runs ~100 cyc/phase overhead at 62% MfmaUtil.  16 MFMA/phase
// needs a 128x64 wave tile -> 256^2 block tile; M=2048 gives only 128 tiles,
// so split-K=2 -> 256 blocks = 1/CU, fp32 atomicAdd epilogue onto zeroed C.
// Schedule/K-tile (BK=64, dbuf = tile&1): 4 phases x {ds_read 8/8/4/4;
// stage 3/3/2/0 half-chunks of tile t+1; barrier; lgkmcnt(0); setprio;
// 16 MFMA; setprio; barrier}; tile-end vmcnt(0) (newest stage ~1 phase old).
// All staging involution / fragment / C-lane formulas carried from R9/R13
// (row&7 == fr&7 still holds; offsets scale only).
// ---------------------------------------------------------------------------
#define BK 64
#define NT_BLK 32                        // 2048 K per block / 64
#define DBUF 32768                       // elems per buffer (A 16384 + B 16384)

#define MF(i, j, A_, B_) acc[i][j] = __builtin_amdgcn_mfma_f32_16x16x32_bf16(A_, B_, acc[i][j], 0, 0, 0)
#define ROW4(i, A_, B0_, B1_, B2_, B3_) \
    MF(i, 0, A_, B0_); MF(i, 1, A_, B1_); MF(i, 2, A_, B2_); MF(i, 3, A_, B3_)

__global__ __launch_bounds__(512, 2) void gemm_bt_kernel(
        const uint16_t* __restrict__ A,   // [2048][4096] bf16
        const uint16_t* __restrict__ B,   // [4096][4096] bf16 (row-major [N][K])
        float* __restrict__ C) {          // [2048][4096] fp32 (pre-zeroed)
    __shared__ uint16_t lds[2 * DBUF];    // 128 KiB

    const int tid  = threadIdx.x;
    const int wave = tid >> 6;            // 0..7
    const int lane = tid & 63;
    const int wm   = wave >> 2;           // 0..1: A-row half (128 rows)
    const int wn   = wave & 3;            // 0..3: B-col quarter (64 cols)

    // XCD swizzle (bijective, 256%8==0); consecutive swz = same output tile's
    // two K-halves -> same XCD L2 for C atomics + A/B panels.
    const int wgid = blockIdx.x;
    const int swz  = (wgid & 7) * 32 + (wgid >> 3);
    const int tile = swz >> 1;            // 0..127
    const int ks   = swz & 1;             // K-half
    const int bm0  = (tile >> 4) * 256;   // 8 row-tiles
    const int bn0  = (tile & 15) * 256;   // 16 col-tiles
    const int kb   = ks * 2048;

    // ---- staging (R9 involution): LDS[r][q] <- global[r][q^(r&7)] ----
    const int srow = wave * 8 + (lane >> 3);             // 0..63 per chunk
    const int xcol = ((lane & 7) ^ (lane >> 3)) << 3;
    const uint16_t* gA = A + (size_t)(bm0 + srow) * K_DIM + kb + xcol;
    const uint16_t* gB = B + (size_t)(bn0 + srow) * K_DIM + kb + xcol;
    const int ldsw = wave * 512;          // per-call wave slot inside 4096-chunk

    // ---- fragment addressing (R9-exact; row&7 == fr&7) ----
    const int fr  = lane & 15;
    const int ko  = (lane >> 4) << 3;
    const int sk0 = (ko)      ^ ((fr & 7) << 3);
    const int sk1 = (32 + ko) ^ ((fr & 7) << 3);
    const int ao0 = (wm * 128 +   0 + fr) * 64;
    const int ao1 = (wm * 128 +  16 + fr) * 64;
    const int ao2 = (wm * 128 +  32 + fr) * 64;
    const int ao3 = (wm * 128 +  48 + fr) * 64;
    const int ao4 = (wm * 128 +  64 + fr) * 64;
    const int ao5 = (wm * 128 +  80 + fr) * 64;
    const int ao6 = (wm * 128 +  96 + fr) * 64;
    const int ao7 = (wm * 128 + 112 + fr) * 64;
    const int bo0 = 16384 + (wn * 64 +  0 + fr) * 64;
    const int bo1 = 16384 + (wn * 64 + 16 + fr) * 64;
    const int bo2 = 16384 + (wn * 64 + 32 + fr) * 64;
    const int bo3 = 16384 + (wn * 64 + 48 + fr) * 64;

    floatx4 acc[8][4];
#pragma unroll
    for (int i = 0; i < 8; ++i)
#pragma unroll
        for (int j = 0; j < 4; ++j) acc[i][j] = {0.f, 0.f, 0.f, 0.f};

    // ---- prologue: stage tile 0 -> dbuf0 (A c0-3, B c0-3), drain ----
#pragma unroll
    for (int c = 0; c < 4; ++c)
        load_lds16(gA + (size_t)(c * 64) * K_DIM, &lds[c * 4096 + ldsw]);
#pragma unroll
    for (int c = 0; c < 4; ++c)
        load_lds16(gB + (size_t)(c * 64) * K_DIM, &lds[16384 + c * 4096 + ldsw]);
    asm volatile("s_waitcnt vmcnt(0)" ::: "memory");
    __builtin_amdgcn_s_barrier();

    for (int t = 0; t < NT_BLK; ++t) {
        const int  cb = (t & 1) << 15;            // compute buffer
        const int  sb = cb ^ DBUF;                // stage buffer (tile t+1)
        const bool pf = (t + 1 < NT_BLK);
        const int  kt = (t + 1) * BK;             // stage k offset

        // ---- P1: read A0-3 s0 + B0-3 s0 (8); stage A c0,c1,c2 ----
        short8 a0 = *(const short8*)&lds[cb + ao0 + sk0];
        short8 a1 = *(const short8*)&lds[cb + ao1 + sk0];
        short8 a2 = *(const short8*)&lds[cb + ao2 + sk0];
        short8 a3 = *(const short8*)&lds[cb + ao3 + sk0];
        short8 b0 = *(const short8*)&lds[cb + bo0 + sk0];
        short8 b1 = *(const short8*)&lds[cb + bo1 + sk0];
        short8 b2 = *(const short8*)&lds[cb + bo2 + sk0];
        short8 b3 = *(const short8*)&lds[cb + bo3 + sk0];
        if (pf) {
            load_lds16(gA + kt,                        &lds[sb + ldsw]);
            load_lds16(gA + kt + (size_t) 64 * K_DIM,  &lds[sb + 4096 + ldsw]);
            load_lds16(gA + kt + (size_t)128 * K_DIM,  &lds[sb + 8192 + ldsw]);
        }
        __builtin_amdgcn_s_barrier();
        asm volatile("s_waitcnt lgkmcnt(0)");
        __builtin_amdgcn_s_setprio(1);
        ROW4(0, a0, b0, b1, b2, b3);
        ROW4(1, a1, b0, b1, b2, b3);
        ROW4(2, a2, b0, b1, b2, b3);
        ROW4(3, a3, b0, b1, b2, b3);
        __builtin_amdgcn_s_setprio(0);
        __builtin_amdgcn_s_barrier();

        // ---- P2: read A0-3 s1 + B0-3 s1 (8); stage A c3, B c0,c1 ----
        short8 c0 = *(const short8*)&lds[cb + ao0 + sk1];
        short8 c1 = *(const short8*)&lds[cb + ao1 + sk1];
        short8 c2 = *(const short8*)&lds[cb + ao2 + sk1];
        short8 c3 = *(const short8*)&lds[cb + ao3 + sk1];
        short8 d0 = *(const short8*)&lds[cb + bo0 + sk1];
        short8 d1 = *(const short8*)&lds[cb + bo1 + sk1];
        short8 d2 = *(const short8*)&lds[cb + bo2 + sk1];
        short8 d3 = *(const short8*)&lds[cb + bo3 + sk1];
        if (pf) {
            load_lds16(gA + kt + (size_t)192 * K_DIM,  &lds[sb + 12288 + ldsw]);
            load_lds16(gB + kt,                        &lds[sb + 16384 + ldsw]);
            load_lds16(gB + kt + (size_t) 64 * K_DIM,  &lds[sb + 20480 + ldsw]);
        }
        __builtin_amdgcn_s_barrier();
        asm volatile("s_waitcnt lgkmcnt(0)");
        __builtin_amdgcn_s_setprio(1);
        ROW4(0, c0, d0, d1, d2, d3);
        ROW4(1, c1, d0, d1, d2, d3);
        ROW4(2, c2, d0, d1, d2, d3);
        ROW4(3, c3, d0, d1, d2, d3);
        __builtin_amdgcn_s_setprio(0);
        __builtin_amdgcn_s_barrier();

        // ---- P3: read A4-7 s0 (4); stage B c2,c3 (B s0 regs still live) ----
        short8 e0 = *(const short8*)&lds[cb + ao4 + sk0];
        short8 e1 = *(const short8*)&lds[cb + ao5 + sk0];
        short8 e2 = *(const short8*)&lds[cb + ao6 + sk0];
        short8 e3 = *(const short8*)&lds[cb + ao7 + sk0];
        if (pf) {
            load_lds16(gB + kt + (size_t)128 * K_DIM,  &lds[sb + 24576 + ldsw]);
            load_lds16(gB + kt + (size_t)192 * K_DIM,  &lds[sb + 28672 + ldsw]);
        }
        __builtin_amdgcn_s_barrier();
        asm volatile("s_waitcnt lgkmcnt(0)");
        __builtin_amdgcn_s_setprio(1);
        ROW4(4, e0, b0, b1, b2, b3);
        ROW4(5, e1, b0, b1, b2, b3);
        ROW4(6, e2, b0, b1, b2, b3);
        ROW4(7, e3, b0, b1, b2, b3);
        __builtin_amdgcn_s_setprio(0);
        __builtin_amdgcn_s_barrier();

        // ---- P4: read A4-7 s1 (4); no stage; tile-end drain ----
        short8 f0 = *(const short8*)&lds[cb + ao4 + sk1];
        short8 f1 = *(const short8*)&lds[cb + ao5 + sk1];
        short8 f2 = *(const short8*)&lds[cb + ao6 + sk1];
        short8 f3 = *(const short8*)&lds[cb + ao7 + sk1];
        __builtin_amdgcn_s_barrier();
        asm volatile("s_waitcnt lgkmcnt(0)");
        __builtin_amdgcn_s_setprio(1);
        ROW4(4, f0, d0, d1, d2, d3);
        ROW4(5, f1, d0, d1, d2, d3);
        ROW4(6, f2, d0, d1, d2, d3);
        ROW4(7, f3, d0, d1, d2, d3);
        __builtin_amdgcn_s_setprio(0);
        if (pf) {
            // newest stage issued in P3 (~1 phase / ~600 cyc ago, mostly L2-hit)
            asm volatile("s_waitcnt vmcnt(0)" ::: "memory");
            __builtin_amdgcn_s_barrier();
        }
    }

    // epilogue: C/D layout col=lane&15, row=(lane>>4)*4+reg [m89/m91];
    // fp32 atomic accumulate (split-K partner adds the other K-half).
    const int cn  = lane & 15;
    const int rb4 = (lane >> 4) * 4;
#pragma unroll
    for (int i = 0; i < 8; ++i)
#pragma unroll
        for (int j = 0; j < 4; ++j)
#pragma unroll
            for (int r = 0; r < 4; ++r) {
                const int row = bm0 + wm * 128 + i * 16 + rb4 + r;
                const int col = bn0 + wn * 64 + j * 16 + cn;
                atomicAdd(&C[(size_t)row * O_FEAT + col], acc[i][j][r]);
            }
}

// ---------------------------------------------------------------------------
extern "C" void kernel_launch(void* const* d_in, const int* in_sizes, int n_in,
                              void* d_out, int out_size, void* d_ws, size_t ws_size,
                              hipStream_t stream) {
    const float* x      = (const float*)d_in[0];
    const void*  packed = d_in[1];
    const float* scales = (const float*)d_in[2];
    const void*  vals   = d_in[3];
    const int*   rows   = (const int*)d_in[4];
    const int*   cols   = (const int*)d_in[5];
    const float* alpha  = (const float*)d_in[6];
    float*       out    = (float*)d_out;
    const int nnz = in_sizes[3];

    uint16_t* W  = (uint16_t*)d_ws;                                        // 32 MB
    uint16_t* Xb = (uint16_t*)((char*)d_ws + (size_t)O_FEAT * I_FEAT * 2); // 16 MB

    // 1) dequant int4 -> bf16 W
    dequant_kernel<<<8192, 256, 0, stream>>>(packed, scales, W);
    // 2) fused: scatter residual into W + x -> bf16 Xb + zero C
    scatter_xconv_zero_kernel<<<K2_BLOCKS, 256, 0, stream>>>(
        vals, rows, cols, alpha, x, W, Xb, out, nnz);
    // 3) GEMM split-K=2: out += Xb * W^T (256 blocks, 1/CU)
    gemm_bt_kernel<<<256, 512, 0, stream>>>(Xb, W, out);
}